// Round 1
// baseline (608.913 us; speedup 1.0000x reference)
//
#include <hip/hip_runtime.h>
#include <math.h>

#define N_NODES 100000
#define N_RELS  3
#define N_EDGES 400000
#define D       128
#define ELL_W   32
#define OVF_CAP 4096

__global__ void zero_kernel(int* cnt_out, int* cnt_in, int* cursor, int* ovf_cnt) {
    int i = blockIdx.x * blockDim.x + threadIdx.x;
    if (i < N_NODES) { cnt_out[i] = 0; cnt_in[i] = 0; cursor[i] = 0; }
    if (i == 0) *ovf_cnt = 0;
}

__global__ void degree_kernel(const int* __restrict__ src, const int* __restrict__ dst,
                              int* cnt_out, int* cnt_in) {
    int e = blockIdx.x * blockDim.x + threadIdx.x;
    if (e < N_EDGES) {
        atomicAdd(&cnt_out[src[e]], 1);
        atomicAdd(&cnt_in[dst[e]], 1);
    }
}

__global__ void rsqrt_kernel(const int* __restrict__ cnt_out, const int* __restrict__ cnt_in,
                             float* __restrict__ rdo, float* __restrict__ rdi) {
    int n = blockIdx.x * blockDim.x + threadIdx.x;
    if (n < N_NODES) {
        rdo[n] = rsqrtf((float)max(cnt_out[n], 1));
        rdi[n] = rsqrtf((float)max(cnt_in[n], 1));
    }
}

__global__ void fill_kernel(const int* __restrict__ src, const int* __restrict__ dst,
                            int* cursor, int* __restrict__ ell, int* ovf_cnt, int2* ovf) {
    int e = blockIdx.x * blockDim.x + threadIdx.x;
    if (e < N_EDGES) {
        int s = src[e], t = dst[e];
        int p = atomicAdd(&cursor[t], 1);
        if (p < ELL_W) {
            ell[t * ELL_W + p] = s;
        } else {
            int i = atomicAdd(ovf_cnt, 1);
            if (i < OVF_CAP) ovf[i] = make_int2(s, t);
        }
    }
}

// One wave per node: gather+sum x[src]*rsqrt(deg_out[src]) rows, float2/lane.
__global__ void gather_kernel(const float* __restrict__ x, const int* __restrict__ ell,
                              const int* __restrict__ cnt_in, const float* __restrict__ rdo,
                              float* __restrict__ agg) {
    int wave = threadIdx.x >> 6;   // 4 waves per block
    int lane = threadIdx.x & 63;
    int n = blockIdx.x * 4 + wave;
    if (n >= N_NODES) return;
    int cnt = min(cnt_in[n], ELL_W);
    int eidx = 0;
    float sc = 0.f;
    if (lane < cnt) {
        eidx = ell[n * ELL_W + lane];
        sc = rdo[eidx];
    }
    float accx = 0.f, accy = 0.f;
    for (int i = 0; i < cnt; ++i) {
        int s = __shfl(eidx, i);
        float scale = __shfl(sc, i);
        const float2 v = *(const float2*)(x + (size_t)s * D + lane * 2);
        accx = fmaf(v.x, scale, accx);
        accy = fmaf(v.y, scale, accy);
    }
    float2 o; o.x = accx; o.y = accy;
    *(float2*)(agg + (size_t)n * D + lane * 2) = o;
}

// Rare path: edges that overflowed ELL_W (in-degree > 32). Runs after gather
// (stream-ordered), atomically adds into agg. Usually zero work.
__global__ void ovf_kernel(const float* __restrict__ x, const float* __restrict__ rdo,
                           const int* __restrict__ ovf_cnt, const int2* __restrict__ ovf,
                           float* agg) {
    int m = min(*ovf_cnt, OVF_CAP);
    int total = m * 64;
    for (int idx = blockIdx.x * blockDim.x + threadIdx.x; idx < total;
         idx += blockDim.x * gridDim.x) {
        int ent = idx >> 6, lane = idx & 63;
        int s = ovf[ent].x, t = ovf[ent].y;
        float scale = rdo[s];
        const float2 v = *(const float2*)(x + (size_t)s * D + lane * 2);
        atomicAdd(&agg[(size_t)t * D + lane * 2 + 0], v.x * scale);
        atomicAdd(&agg[(size_t)t * D + lane * 2 + 1], v.y * scale);
    }
}

// out (+)= ( rdi[n] * (agg[n,:] @ W) + b ) / 3.  W staged in LDS (64 KB).
// 256 threads: 8 rows x 32 col-groups (4 cols each); 64 rows per block.
__global__ void gemm_kernel(const float* __restrict__ agg, const float* __restrict__ W,
                            const float* __restrict__ b, const float* __restrict__ rdi,
                            float* __restrict__ out, int first) {
    __shared__ float Wl[D * D];
    for (int i = threadIdx.x * 4; i < D * D; i += 256 * 4) {
        *(float4*)&Wl[i] = *(const float4*)&W[i];
    }
    __syncthreads();

    const int rg = threadIdx.x >> 5;   // 0..7
    const int cg = threadIdx.x & 31;   // col group, 4 cols each
    const int row0 = blockIdx.x * 64;
    const float inv3 = 1.f / 3.f;

    float4 bb = *(const float4*)(b + cg * 4);

    for (int rr = 0; rr < 64; rr += 8) {
        int n = row0 + rr + rg;
        if (n >= N_NODES) continue;
        const float* arow = agg + (size_t)n * D;
        float4 acc; acc.x = acc.y = acc.z = acc.w = 0.f;
        #pragma unroll
        for (int k4 = 0; k4 < 32; ++k4) {
            float4 a = *(const float4*)(arow + k4 * 4);
            const float* wb = &Wl[(k4 * 4) * D + cg * 4];
            float4 w0 = *(const float4*)(wb);
            float4 w1 = *(const float4*)(wb + D);
            float4 w2 = *(const float4*)(wb + 2 * D);
            float4 w3 = *(const float4*)(wb + 3 * D);
            acc.x = fmaf(a.x, w0.x, acc.x); acc.y = fmaf(a.x, w0.y, acc.y);
            acc.z = fmaf(a.x, w0.z, acc.z); acc.w = fmaf(a.x, w0.w, acc.w);
            acc.x = fmaf(a.y, w1.x, acc.x); acc.y = fmaf(a.y, w1.y, acc.y);
            acc.z = fmaf(a.y, w1.z, acc.z); acc.w = fmaf(a.y, w1.w, acc.w);
            acc.x = fmaf(a.z, w2.x, acc.x); acc.y = fmaf(a.z, w2.y, acc.y);
            acc.z = fmaf(a.z, w2.z, acc.z); acc.w = fmaf(a.z, w2.w, acc.w);
            acc.x = fmaf(a.w, w3.x, acc.x); acc.y = fmaf(a.w, w3.y, acc.y);
            acc.z = fmaf(a.w, w3.z, acc.z); acc.w = fmaf(a.w, w3.w, acc.w);
        }
        float s = rdi[n];
        float4 val;
        val.x = (fmaf(s, acc.x, bb.x)) * inv3;
        val.y = (fmaf(s, acc.y, bb.y)) * inv3;
        val.z = (fmaf(s, acc.z, bb.z)) * inv3;
        val.w = (fmaf(s, acc.w, bb.w)) * inv3;
        float* op = out + (size_t)n * D + cg * 4;
        if (first) {
            *(float4*)op = val;
        } else {
            float4 o = *(const float4*)op;
            o.x += val.x; o.y += val.y; o.z += val.z; o.w += val.w;
            *(float4*)op = o;
        }
    }
}

extern "C" void kernel_launch(void* const* d_in, const int* in_sizes, int n_in,
                              void* d_out, int out_size, void* d_ws, size_t ws_size,
                              hipStream_t stream) {
    const float* x     = (const float*)d_in[0];
    const int*   edges = (const int*)d_in[1];   // [R][2][E] int32
    const float* W     = (const float*)d_in[2]; // [R][D][D]
    const float* b     = (const float*)d_in[3]; // [R][D]
    float* out = (float*)d_out;

    char* ws = (char*)d_ws;
    size_t off = 0;
    auto alloc = [&](size_t bytes) -> void* {
        void* p = ws + off;
        off += (bytes + 255) & ~(size_t)255;
        return p;
    };
    int*   cnt_out = (int*)alloc((size_t)N_NODES * 4);
    int*   cnt_in  = (int*)alloc((size_t)N_NODES * 4);
    int*   cursor  = (int*)alloc((size_t)N_NODES * 4);
    float* rdo     = (float*)alloc((size_t)N_NODES * 4);
    float* rdi     = (float*)alloc((size_t)N_NODES * 4);
    int*   ovf_cnt = (int*)alloc(256);
    int2*  ovf     = (int2*)alloc((size_t)OVF_CAP * 8);
    int*   ell     = (int*)alloc((size_t)N_NODES * ELL_W * 4);
    float* agg     = (float*)alloc((size_t)N_NODES * D * 4);

    for (int r = 0; r < N_RELS; ++r) {
        const int* src = edges + (size_t)(r * 2 + 0) * N_EDGES;
        const int* dst = edges + (size_t)(r * 2 + 1) * N_EDGES;
        zero_kernel<<<(N_NODES + 255) / 256, 256, 0, stream>>>(cnt_out, cnt_in, cursor, ovf_cnt);
        degree_kernel<<<(N_EDGES + 255) / 256, 256, 0, stream>>>(src, dst, cnt_out, cnt_in);
        rsqrt_kernel<<<(N_NODES + 255) / 256, 256, 0, stream>>>(cnt_out, cnt_in, rdo, rdi);
        fill_kernel<<<(N_EDGES + 255) / 256, 256, 0, stream>>>(src, dst, cursor, ell, ovf_cnt, ovf);
        gather_kernel<<<(N_NODES + 3) / 4, 256, 0, stream>>>(x, ell, cnt_in, rdo, agg);
        ovf_kernel<<<8, 256, 0, stream>>>(x, rdo, ovf_cnt, ovf, agg);
        gemm_kernel<<<(N_NODES + 63) / 64, 256, 0, stream>>>(
            agg, W + (size_t)r * D * D, b + (size_t)r * D, rdi, out, r == 0 ? 1 : 0);
    }
}

// Round 2
// 291.618 us; speedup vs baseline: 2.0880x; 2.0880x over previous
//
#include <hip/hip_runtime.h>
#include <math.h>

#define N_NODES 100000
#define N_RELS  3
#define N_EDGES 400000
#define D       128
#define ELL_W   24
#define OVF_CAP 8192

typedef __attribute__((ext_vector_type(8))) short bf16x8;
typedef __attribute__((ext_vector_type(4))) float f32x4;

static __device__ __forceinline__ ushort f2bf(float f) {
    uint u = __builtin_bit_cast(uint, f);
    u = u + 0x7fffu + ((u >> 16) & 1u);   // round-to-nearest-even
    return (ushort)(u >> 16);
}
static __device__ __forceinline__ float bf_lo(uint u) {  // low ushort -> float
    return __builtin_bit_cast(float, u << 16);
}
static __device__ __forceinline__ float bf_hi(uint u) {  // high ushort -> float
    return __builtin_bit_cast(float, u & 0xffff0000u);
}

// W transpose + bf16 convert: Wt[r][j][k] = bf16(W[r][k][j]); bsum[j] = mean_r b[r][j]
__global__ void prep_w_kernel(const float* __restrict__ W, const float* __restrict__ b,
                              ushort* __restrict__ Wt, float* __restrict__ bsum) {
    int id = blockIdx.x * 256 + threadIdx.x;
    if (id < 3 * D * D) {
        int r = id >> 14;
        int rem = id & 16383;
        int k = rem >> 7, j = rem & 127;
        Wt[r * 16384 + j * 128 + k] = f2bf(W[id]);
    }
    if (blockIdx.x == 0 && threadIdx.x < D) {
        int j = threadIdx.x;
        bsum[j] = (b[j] + b[D + j] + b[2 * D + j]) * (1.0f / 3.0f);
    }
}

// One pass over all 3*E edges: out-degree count (src) + ELL fill (dst).
__global__ void fill_kernel(const int* __restrict__ edges, int* __restrict__ cnt_out,
                            int* __restrict__ cursor, int* __restrict__ ell,
                            int* __restrict__ ovf_cnt, int2* __restrict__ ovf) {
    int e = blockIdx.x * 256 + threadIdx.x;
    int rel = blockIdx.y;
    if (e >= N_EDGES) return;
    int s = edges[(size_t)(rel * 2 + 0) * N_EDGES + e];
    int t = edges[(size_t)(rel * 2 + 1) * N_EDGES + e];
    atomicAdd(cnt_out + rel * N_NODES + s, 1);
    int p = atomicAdd(cursor + rel * N_NODES + t, 1);
    if (p < ELL_W) {
        ell[(size_t)(rel * N_NODES + t) * ELL_W + p] = s;
    } else {
        int i = atomicAdd(ovf_cnt, 1);
        if (i < OVF_CAP) ovf[i] = make_int2(s, t | (rel << 20));
    }
}

__global__ void rsqrt_kernel(const int* __restrict__ cnt_out, const int* __restrict__ cursor,
                             float* __restrict__ rdo, float* __restrict__ rdi) {
    int i = blockIdx.x * 256 + threadIdx.x;
    if (i < 3 * N_NODES) {
        rdo[i] = rsqrtf((float)max(cnt_out[i], 1));
        rdi[i] = rsqrtf((float)max(cursor[i], 1));
    }
}

// h[n, rel*128+j] = bf16( rdo[rel][n] * sum_k x[n,k] W[rel][k][j] )
// 2-pass bf16 split on A (x) for ~fp32 A precision; W single bf16.
// Block: 256 thr = 4 waves (2x2), tile 128 rows x 128 cols (one relation).
__global__ __launch_bounds__(256) void gemm_h_kernel(
    const float* __restrict__ x, const ushort* __restrict__ Wt,
    const float* __restrict__ rdo, ushort* __restrict__ h) {
    __shared__ ushort Bt[128 * 128];   // Wt[rel] swizzled: [j][k]
    const int rel = blockIdx.x;
    const int n0  = blockIdx.y * 128;
    const int tid = threadIdx.x;

    // stage W^T (bf16) into LDS with XOR swizzle on (j&7)
    {
        const ushort* Wg = Wt + rel * 16384;
        #pragma unroll
        for (int c = 0; c < 8; ++c) {
            int id = c * 256 + tid;        // 16B chunk id, 0..2047
            int j = id >> 4, k8 = id & 15;
            uint4 v = *(const uint4*)(Wg + j * 128 + k8 * 8);
            int ba = (j * 256 + k8 * 16) ^ ((j & 7) << 4);
            *(uint4*)((char*)Bt + ba) = v;
        }
    }
    __syncthreads();

    const int w = tid >> 6, l = tid & 63;
    const int wrow = (w >> 1) * 64, wcol = (w & 1) * 64;
    const int lr = l & 15, lk = (l >> 4) * 8;

    f32x4 acc[4][4];
    #pragma unroll
    for (int fi = 0; fi < 4; ++fi)
        #pragma unroll
        for (int fj = 0; fj < 4; ++fj)
            acc[fi][fj] = (f32x4){0.f, 0.f, 0.f, 0.f};

    #pragma unroll
    for (int ks = 0; ks < 4; ++ks) {
        bf16x8 bfr[4];
        #pragma unroll
        for (int fj = 0; fj < 4; ++fj) {
            int j = wcol + fj * 16 + lr;
            int ba = (j * 256 + (ks * 32 + lk) * 2) ^ ((j & 7) << 4);
            bfr[fj] = *(bf16x8*)((char*)Bt + ba);
        }
        #pragma unroll
        for (int fi = 0; fi < 4; ++fi) {
            int row = n0 + wrow + fi * 16 + lr;
            row = min(row, N_NODES - 1);
            const float* xp = x + (size_t)row * 128 + ks * 32 + lk;
            float4 va = *(const float4*)xp;
            float4 vb = *(const float4*)(xp + 4);
            float fs[8] = {va.x, va.y, va.z, va.w, vb.x, vb.y, vb.z, vb.w};
            bf16x8 ah, al;
            #pragma unroll
            for (int q = 0; q < 8; ++q) {
                ushort hq = f2bf(fs[q]);
                float hf = __builtin_bit_cast(float, (uint)hq << 16);
                ah[q] = (short)hq;
                al[q] = (short)f2bf(fs[q] - hf);
            }
            #pragma unroll
            for (int fj = 0; fj < 4; ++fj) {
                acc[fi][fj] = __builtin_amdgcn_mfma_f32_16x16x32_bf16(ah, bfr[fj], acc[fi][fj], 0, 0, 0);
                acc[fi][fj] = __builtin_amdgcn_mfma_f32_16x16x32_bf16(al, bfr[fj], acc[fi][fj], 0, 0, 0);
            }
        }
    }

    // epilogue: scale rows by rdo, store bf16. C/D: col=lane&15, row=(lane>>4)*4+i
    const int cr4 = (l >> 4) * 4;
    #pragma unroll
    for (int fi = 0; fi < 4; ++fi) {
        int rbase = n0 + wrow + fi * 16 + cr4;
        float sc[4];
        #pragma unroll
        for (int i = 0; i < 4; ++i) {
            int row = rbase + i;
            sc[i] = (row < N_NODES) ? rdo[rel * N_NODES + row] : 0.f;
        }
        #pragma unroll
        for (int fj = 0; fj < 4; ++fj) {
            int col = wcol + fj * 16 + lr;
            #pragma unroll
            for (int i = 0; i < 4; ++i) {
                int row = rbase + i;
                if (row < N_NODES)
                    h[(size_t)row * 384 + rel * 128 + col] = f2bf(acc[fi][fj][i] * sc[i]);
            }
        }
    }
}

// out[n,:] = (1/3) sum_r rdi_r[n] * sum_{e:dst=n} h[src_e, r*128:(r+1)*128]  + bsum
// One wave per node; lane handles cols 2l, 2l+1 (bf16x2 load).
__global__ __launch_bounds__(256) void gather_kernel(
    const ushort* __restrict__ h, const int* __restrict__ cursor,
    const int* __restrict__ ell, const float* __restrict__ rdi,
    const float* __restrict__ bsum, float* __restrict__ out) {
    int w = threadIdx.x >> 6, l = threadIdx.x & 63;
    int n = blockIdx.x * 4 + w;
    if (n >= N_NODES) return;
    float ox = 0.f, oy = 0.f;
    #pragma unroll
    for (int r = 0; r < 3; ++r) {
        int base = r * N_NODES + n;
        int cnt = min(cursor[base], ELL_W);
        int e = 0;
        if (l < cnt) e = ell[(size_t)base * ELL_W + l];
        float ax = 0.f, ay = 0.f;
        int i = 0;
        for (; i + 2 <= cnt; i += 2) {
            int s0 = __shfl(e, i), s1 = __shfl(e, i + 1);
            uint u0 = *(const uint*)(h + (size_t)s0 * 384 + r * 128 + 2 * l);
            uint u1 = *(const uint*)(h + (size_t)s1 * 384 + r * 128 + 2 * l);
            ax += bf_lo(u0); ay += bf_hi(u0);
            ax += bf_lo(u1); ay += bf_hi(u1);
        }
        if (i < cnt) {
            int s0 = __shfl(e, i);
            uint u0 = *(const uint*)(h + (size_t)s0 * 384 + r * 128 + 2 * l);
            ax += bf_lo(u0); ay += bf_hi(u0);
        }
        float sc = rdi[base];
        ox = fmaf(ax, sc, ox);
        oy = fmaf(ay, sc, oy);
    }
    float2 bs = *(const float2*)(bsum + 2 * l);
    float2 o;
    o.x = ox * (1.f / 3.f) + bs.x;
    o.y = oy * (1.f / 3.f) + bs.y;
    *(float2*)(out + (size_t)n * 128 + 2 * l) = o;
}

// Rare overflow path (in-degree > ELL_W): atomic add into out.
__global__ void ovf_kernel(const ushort* __restrict__ h, const float* __restrict__ rdi,
                           const int* __restrict__ ovf_cnt, const int2* __restrict__ ovf,
                           float* out) {
    int m = min(*ovf_cnt, OVF_CAP);
    int total = m * 64;
    for (int idx = blockIdx.x * blockDim.x + threadIdx.x; idx < total;
         idx += blockDim.x * gridDim.x) {
        int ent = idx >> 6, l = idx & 63;
        int s = ovf[ent].x;
        int packed = ovf[ent].y;
        int t = packed & 0xFFFFF, r = packed >> 20;
        uint u = *(const uint*)(h + (size_t)s * 384 + r * 128 + 2 * l);
        float sc = rdi[r * N_NODES + t] * (1.f / 3.f);
        atomicAdd(out + (size_t)t * 128 + 2 * l + 0, bf_lo(u) * sc);
        atomicAdd(out + (size_t)t * 128 + 2 * l + 1, bf_hi(u) * sc);
    }
}

extern "C" void kernel_launch(void* const* d_in, const int* in_sizes, int n_in,
                              void* d_out, int out_size, void* d_ws, size_t ws_size,
                              hipStream_t stream) {
    const float* x     = (const float*)d_in[0];
    const int*   edges = (const int*)d_in[1];   // [R][2][E] int32
    const float* W     = (const float*)d_in[2]; // [R][D][D]
    const float* b     = (const float*)d_in[3]; // [R][D]
    float* out = (float*)d_out;

    char* ws = (char*)d_ws;
    size_t off = 0;
    auto alloc = [&](size_t bytes) -> void* {
        void* p = ws + off;
        off += (bytes + 255) & ~(size_t)255;
        return p;
    };
    int*   cnt_out = (int*)alloc((size_t)3 * N_NODES * 4);
    int*   cursor  = (int*)alloc((size_t)3 * N_NODES * 4);
    int*   ovf_cnt = (int*)alloc(256);
    size_t zero_bytes = off;                       // memset cnt_out..ovf_cnt
    float* rdo     = (float*)alloc((size_t)3 * N_NODES * 4);
    float* rdi     = (float*)alloc((size_t)3 * N_NODES * 4);
    float* bsum    = (float*)alloc((size_t)D * 4);
    ushort* Wt     = (ushort*)alloc((size_t)3 * D * D * 2);
    int2*  ovf     = (int2*)alloc((size_t)OVF_CAP * 8);
    int*   ell     = (int*)alloc((size_t)3 * N_NODES * ELL_W * 4);
    ushort* h      = (ushort*)alloc((size_t)N_NODES * 3 * D * 2);

    hipMemsetAsync(ws, 0, zero_bytes, stream);
    prep_w_kernel<<<192, 256, 0, stream>>>(W, b, Wt, bsum);
    fill_kernel<<<dim3((N_EDGES + 255) / 256, 3), 256, 0, stream>>>(
        edges, cnt_out, cursor, ell, ovf_cnt, ovf);
    rsqrt_kernel<<<(3 * N_NODES + 255) / 256, 256, 0, stream>>>(cnt_out, cursor, rdo, rdi);
    gemm_h_kernel<<<dim3(3, (N_NODES + 127) / 128), 256, 0, stream>>>(x, Wt, rdo, h);
    gather_kernel<<<(N_NODES + 3) / 4, 256, 0, stream>>>(h, cursor, ell, rdi, bsum, out);
    ovf_kernel<<<16, 256, 0, stream>>>(h, rdi, ovf_cnt, ovf, out);
}